// Round 1
// 3082.688 us; speedup vs baseline: 1.1649x; 1.1649x over previous
//
#include <hip/hip_runtime.h>
#include <hip/hip_bf16.h>
#include <stdint.h>

#define N_TOK 16384
#define C_DIM 1024
#define NH    16
#define HD    64
#define WSZ   512
#define SHIFT_T 256

typedef __bf16 bf16x8 __attribute__((ext_vector_type(8)));
typedef float  f32x4  __attribute__((ext_vector_type(4)));
typedef unsigned short ushort_t;

// float -> bf16 bits, round-to-nearest-even
__device__ __forceinline__ ushort_t f2bf(float f) {
    unsigned int x = __float_as_uint(f);
    unsigned int lsb = (x >> 16) & 1u;
    x += 0x7fffu + lsb;
    return (ushort_t)(x >> 16);
}

__device__ __forceinline__ float gelu_tanh(float v) {
    float v3 = v * v * v;
    float t = tanhf(0.7978845608028654f * (v + 0.044715f * v3));
    return 0.5f * v * (1.0f + t);
}

// ---------------------------------------------------------------------------
// Weight transpose + fp32->bf16: W[K][M] f32  ->  WT[M][K] bf16
// ---------------------------------------------------------------------------
__global__ __launch_bounds__(256) void wt_transpose(const float* __restrict__ W,
                                                    ushort_t* __restrict__ WT,
                                                    int K, int M) {
    __shared__ float tile[64][65];
    const int k0 = blockIdx.y * 64;
    const int m0 = blockIdx.x * 64;
    const int tx = threadIdx.x & 63;
    const int ty = threadIdx.x >> 6;   // 0..3
#pragma unroll
    for (int p = 0; p < 16; p++) {
        tile[p * 4 + ty][tx] = W[(size_t)(k0 + p * 4 + ty) * M + m0 + tx];
    }
    __syncthreads();
#pragma unroll
    for (int p = 0; p < 16; p++) {
        WT[(size_t)(m0 + p * 4 + ty) * K + k0 + tx] = f2bf(tile[tx][p * 4 + ty]);
    }
}

// ---------------------------------------------------------------------------
// LayerNorm (no affine, eps 1e-6), fp32 in -> bf16 out, with optional roll.
// ---------------------------------------------------------------------------
__global__ __launch_bounds__(256) void ln_kernel(const float* __restrict__ src,
                                                 ushort_t* __restrict__ dst,
                                                 int dstStride, int rollShift) {
    const int row = blockIdx.x;
    const int tid = threadIdx.x;
    float4 v = reinterpret_cast<const float4*>(src + (size_t)row * C_DIM)[tid];
    float s = v.x + v.y + v.z + v.w;
    float q = v.x * v.x + v.y * v.y + v.z * v.z + v.w * v.w;
#pragma unroll
    for (int d = 1; d < 64; d <<= 1) {
        s += __shfl_xor(s, d);
        q += __shfl_xor(q, d);
    }
    __shared__ float red[8];
    if ((tid & 63) == 0) { red[(tid >> 6) * 2] = s; red[(tid >> 6) * 2 + 1] = q; }
    __syncthreads();
    s = red[0] + red[2] + red[4] + red[6];
    q = red[1] + red[3] + red[5] + red[7];
    const float mean = s * (1.0f / C_DIM);
    const float var  = q * (1.0f / C_DIM) - mean * mean;
    const float rs   = rsqrtf(var + 1e-6f);
    const int drow = (row - rollShift) & (N_TOK - 1);
    ushort4 o;
    o.x = f2bf((v.x - mean) * rs);
    o.y = f2bf((v.y - mean) * rs);
    o.z = f2bf((v.z - mean) * rs);
    o.w = f2bf((v.w - mean) * rs);
    reinterpret_cast<ushort4*>(dst + (size_t)drow * dstStride)[tid] = o;
}

// ---------------------------------------------------------------------------
// mv_normal / mv_color fp32 -> bf16 into acat columns
// ---------------------------------------------------------------------------
__global__ __launch_bounds__(256) void cvt_cat(const float* __restrict__ mvn,
                                               const float* __restrict__ mvc,
                                               ushort_t* __restrict__ acat) {
    const int idx = blockIdx.x * 256 + threadIdx.x;
    const float4 v = reinterpret_cast<const float4*>(blockIdx.y ? mvc : mvn)[idx];
    const int row = idx >> 10;
    const int c4  = idx & 1023;
    ushort4 o;
    o.x = f2bf(v.x); o.y = f2bf(v.y); o.z = f2bf(v.z); o.w = f2bf(v.w);
    ushort_t* dst = acat + (size_t)row * 9216 + (blockIdx.y ? 5120 : 1024) + c4 * 4;
    *reinterpret_cast<ushort4*>(dst) = o;
}

// ---------------------------------------------------------------------------
// 256x256-tile 8-phase GEMM: C[N x M] = A[N x K](bf16) @ BT[M x K](bf16)^T + bias
// 8 waves (2M x 4N), BK=64, double-buffered 128 KiB LDS.
// T2: XOR bank-swizzle (inverse-swizzled global src + swizzled ds_read).
// T3+T4: per-phase barrier interleave, counted vmcnt(4) at phases 4/8 only.
// T5: setprio around MFMA clusters. T1: bijective XCD grid swizzle.
// mode 0: outB = bf16(acc+bias)
// mode 1: outB = bf16(gelu(acc+bias))
// mode 2: outF = res + acc + bias (f32)
// rollA: A row = (out_row - 256) mod N
// ---------------------------------------------------------------------------
#define TILE_E (256 * 64)

__global__ __launch_bounds__(512, 2) void gemm256(const ushort_t* __restrict__ A,
                                                  const ushort_t* __restrict__ BT,
                                                  const float* __restrict__ bias,
                                                  const float* res,
                                                  float* outF,
                                                  ushort_t* __restrict__ outB,
                                                  int K, int M, int mode, int rollA) {
    __shared__ ushort_t sA[2 * TILE_E];
    __shared__ ushort_t sB[2 * TILE_E];

    const int tid  = threadIdx.x;
    const int lane = tid & 63;
    const int wv   = tid >> 6;        // 0..7
    const int wm   = wv >> 2;         // 0..1  (M half)
    const int wn   = wv & 3;          // 0..3  (N quarter)
    const int quad = lane >> 4;
    const int l15  = lane & 15;

    // T1: XCD-aware bijective swizzle (all grids have nwg % 8 == 0)
    const int gx  = gridDim.x;
    const int nwg = gx * gridDim.y;
    const int lin = blockIdx.y * gx + blockIdx.x;
    const int cpx = nwg >> 3;
    const int swz = (lin & 7) * cpx + (lin >> 3);
    const int rb  = (swz / gx) * 256;
    const int cb  = (swz % gx) * 256;

    // ---- staging: per thread 4 loads/operand/K-tile; lane l covers
    // row = l*64 + wv*8 + (lane>>3), 16B chunk (lane&7). Global source is
    // inverse-swizzled so the swizzled ds_read below finds linear data.
    const int sr     = lane >> 3;              // 0..7
    const int schunk = (lane & 7) ^ sr;        // pre-swizzled k-chunk
    const ushort_t* gAr[4];
    const ushort_t* gBr[4];
#pragma unroll
    for (int l = 0; l < 4; l++) {
        int rA = rb + l * 64 + wv * 8 + sr;
        if (rollA) rA = (rA + N_TOK - SHIFT_T) & (N_TOK - 1);
        gAr[l] = A + (size_t)rA * K + schunk * 8;
        gBr[l] = BT + (size_t)(cb + l * 64 + wv * 8 + sr) * K + schunk * 8;
    }
    const int ldsStageOff = wv * 8 * 64;       // wave-uniform

    auto stageA = [&](int buf, int t) {
        const int kk = t << 6;
#pragma unroll
        for (int l = 0; l < 4; l++)
            __builtin_amdgcn_global_load_lds(
                (const __attribute__((address_space(1))) void*)(gAr[l] + kk),
                (__attribute__((address_space(3))) void*)(sA + buf * TILE_E + l * 4096 + ldsStageOff),
                16, 0, 0);
    };
    auto stageB = [&](int buf, int t) {
        const int kk = t << 6;
#pragma unroll
        for (int l = 0; l < 4; l++)
            __builtin_amdgcn_global_load_lds(
                (const __attribute__((address_space(1))) void*)(gBr[l] + kk),
                (__attribute__((address_space(3))) void*)(sB + buf * TILE_E + l * 4096 + ldsStageOff),
                16, 0, 0);
    };

    // ---- swizzled fragment readers (bank-conflict-free: 2-way max)
    auto rdA = [&](int buf, int mh, int kh, bf16x8* av) {
        const ushort_t* base = sA + buf * TILE_E;
#pragma unroll
        for (int q = 0; q < 4; q++) {
            const int row = wm * 128 + (mh * 4 + q) * 16 + l15;
            const int e = row * 64 + (((kh * 4 + quad) ^ (l15 & 7)) << 3);
            av[q] = *(const bf16x8*)(base + e);
        }
    };
    auto rdB = [&](int buf, int kh, bf16x8* bv) {
        const ushort_t* base = sB + buf * TILE_E;
#pragma unroll
        for (int n = 0; n < 4; n++) {
            const int row = wn * 64 + n * 16 + l15;
            const int e = row * 64 + (((kh * 4 + quad) ^ (l15 & 7)) << 3);
            bv[n] = *(const bf16x8*)(base + e);
        }
    };

    f32x4 acc[8][4];
    const f32x4 zero = {0.f, 0.f, 0.f, 0.f};
#pragma unroll
    for (int i = 0; i < 8; i++)
#pragma unroll
        for (int j = 0; j < 4; j++) acc[i][j] = zero;

    auto mmac = [&](int mh, bf16x8* av, bf16x8* bv) {
        __builtin_amdgcn_s_setprio(1);
#pragma unroll
        for (int q = 0; q < 4; q++)
#pragma unroll
            for (int n = 0; n < 4; n++)
                acc[mh * 4 + q][n] =
                    __builtin_amdgcn_mfma_f32_16x16x32_bf16(av[q], bv[n], acc[mh * 4 + q][n], 0, 0, 0);
        __builtin_amdgcn_s_setprio(0);
    };

#define BAR()  asm volatile("s_barrier" ::: "memory")
#define LGKM0() do { asm volatile("s_waitcnt lgkmcnt(0)" ::: "memory"); \
                     __builtin_amdgcn_sched_barrier(0); } while (0)

    const int T = K >> 6;              // #64-wide K-tiles (even for all shapes)

    // prologue: tile0 -> buf0 (A+B), tile1 B -> buf1; A of tile1 comes at ph1.
    stageB(0, 0); stageA(0, 0); stageB(1, 1);
    __builtin_amdgcn_s_waitcnt(0x0F74);    // vmcnt(4): tile0 A+B landed
    BAR();

    bf16x8 av[4], bv[4];
    const int nIt = T >> 1;
    for (int i = 0; i < nIt; i++) {
        const int t2 = 2 * i + 2;
        const int t3 = 2 * i + 3;
        // ph1: buf0 A(mh0,kh0) + B(kh0); stage A(buf1, 2i+1)
        rdA(0, 0, 0, av); rdB(0, 0, bv);
        stageA(1, 2 * i + 1);
        BAR(); LGKM0();
        mmac(0, av, bv);
        BAR();
        // ph2: buf0 A(mh1,kh0)
        rdA(0, 1, 0, av);
        BAR(); LGKM0();
        mmac(1, av, bv);
        BAR();
        // ph3: buf0 A(mh0,kh1) + B(kh1)
        rdA(0, 0, 1, av); rdB(0, 1, bv);
        BAR(); LGKM0();
        mmac(0, av, bv);
        BAR();
        // ph4: buf0 A(mh1,kh1); stage B(buf0, t2); counted vmcnt
        rdA(0, 1, 1, av);
        if (t2 < T) { stageB(0, t2); __builtin_amdgcn_s_waitcnt(0x0F74); }
        else        { __builtin_amdgcn_s_waitcnt(0x0F70); }
        BAR(); LGKM0();
        mmac(1, av, bv);
        BAR();
        // ph5: buf1 A(mh0,kh0) + B(kh0); stage A(buf0, t2)
        rdA(1, 0, 0, av); rdB(1, 0, bv);
        if (t2 < T) stageA(0, t2);
        BAR(); LGKM0();
        mmac(0, av, bv);
        BAR();
        // ph6: buf1 A(mh1,kh0)
        rdA(1, 1, 0, av);
        BAR(); LGKM0();
        mmac(1, av, bv);
        BAR();
        // ph7: buf1 A(mh0,kh1) + B(kh1)
        rdA(1, 0, 1, av); rdB(1, 1, bv);
        BAR(); LGKM0();
        mmac(0, av, bv);
        BAR();
        // ph8: buf1 A(mh1,kh1); stage B(buf1, t3); counted vmcnt
        rdA(1, 1, 1, av);
        if (t3 < T) { stageB(1, t3); __builtin_amdgcn_s_waitcnt(0x0F74); }
        else        { __builtin_amdgcn_s_waitcnt(0x0F70); }
        BAR(); LGKM0();
        mmac(1, av, bv);
        BAR();
    }

#undef BAR
#undef LGKM0

    // epilogue: C/D layout col=lane&15, row=quad*4+reg
#pragma unroll
    for (int ni = 0; ni < 4; ni++) {
        const int col = cb + wn * 64 + ni * 16 + l15;
        const float bcol = bias[col];
#pragma unroll
        for (int mi = 0; mi < 8; mi++) {
#pragma unroll
            for (int r = 0; r < 4; r++) {
                const int row = rb + wm * 128 + mi * 16 + quad * 4 + r;
                float v = acc[mi][ni][r] + bcol;
                if (mode == 0) {
                    outB[(size_t)row * M + col] = f2bf(v);
                } else if (mode == 1) {
                    outB[(size_t)row * M + col] = f2bf(gelu_tanh(v));
                } else {
                    outF[(size_t)row * M + col] = res[(size_t)row * M + col] + v;
                }
            }
        }
    }
}

// ---------------------------------------------------------------------------
// Flash-style windowed attention over rolled qkv buffer [16384 x 3072] bf16.
// ---------------------------------------------------------------------------
__global__ __launch_bounds__(256) void attn_kernel(const ushort_t* __restrict__ qkv,
                                                   ushort_t* __restrict__ attn_o) {
    __shared__ ushort_t sQ[128 * 64];
    __shared__ ushort_t sK[64 * 64];
    __shared__ ushort_t sVT[64 * 64];
    __shared__ ushort_t sP[4][32 * 64];

    const int tid  = threadIdx.x;
    const int lane = tid & 63;
    const int wv   = tid >> 6;
    const int quad = lane >> 4;
    const int l15  = lane & 15;

    const int qc = blockIdx.x;
    const int h  = blockIdx.y;
    const int w  = blockIdx.z;
    const int qbase = w * WSZ + qc * 128;

    {
        const int r    = tid >> 1;
        const int half = (tid & 1) * 32;
        const ushort_t* src = qkv + (size_t)(qbase + r) * 3072 + h * 64 + half;
        const uint4* s4 = reinterpret_cast<const uint4*>(src);
        uint4* d4 = reinterpret_cast<uint4*>(sQ + r * 64 + half);
        d4[0] = s4[0]; d4[1] = s4[1]; d4[2] = s4[2]; d4[3] = s4[3];
    }

    f32x4 o[2][4];
    const f32x4 zero = {0.f, 0.f, 0.f, 0.f};
#pragma unroll
    for (int mi = 0; mi < 2; mi++)
#pragma unroll
        for (int ni = 0; ni < 4; ni++) o[mi][ni] = zero;
    float m_st[2][4], l_st[2][4];
#pragma unroll
    for (int mi = 0; mi < 2; mi++)
#pragma unroll
        for (int r = 0; r < 4; r++) { m_st[mi][r] = -3.0e38f; l_st[mi][r] = 0.f; }

    const int wq = wv * 32;

    for (int kt = 0; kt < 8; kt++) {
        __syncthreads();
        {
            const int key = tid >> 2;
            const int dq  = (tid & 3) * 16;
            const size_t rowb = (size_t)(w * WSZ + kt * 64 + key) * 3072;
            const uint4* sk4 = reinterpret_cast<const uint4*>(qkv + rowb + 1024 + h * 64 + dq);
            uint4* dk4 = reinterpret_cast<uint4*>(sK + key * 64 + dq);
            dk4[0] = sk4[0]; dk4[1] = sk4[1];
            const uint4* sv4 = reinterpret_cast<const uint4*>(qkv + rowb + 2048 + h * 64 + dq);
            uint4 a = sv4[0], b = sv4[1];
            const ushort_t* pa = reinterpret_cast<const ushort_t*>(&a);
            const ushort_t* pb = reinterpret_cast<const ushort_t*>(&b);
#pragma unroll
            for (int j = 0; j < 8; j++) {
                sVT[(dq + j) * 64 + key]     = pa[j];
                sVT[(dq + 8 + j) * 64 + key] = pb[j];
            }
        }
        __syncthreads();

        f32x4 s[2][4];
#pragma unroll
        for (int mi = 0; mi < 2; mi++)
#pragma unroll
            for (int ni = 0; ni < 4; ni++) s[mi][ni] = zero;
#pragma unroll
        for (int ks = 0; ks < 2; ks++) {
            bf16x8 aq[2], bk[4];
#pragma unroll
            for (int mi = 0; mi < 2; mi++)
                aq[mi] = *(const bf16x8*)(sQ + (wq + mi * 16 + l15) * 64 + ks * 32 + quad * 8);
#pragma unroll
            for (int ni = 0; ni < 4; ni++)
                bk[ni] = *(const bf16x8*)(sK + (ni * 16 + l15) * 64 + ks * 32 + quad * 8);
#pragma unroll
            for (int mi = 0; mi < 2; mi++)
#pragma unroll
                for (int ni = 0; ni < 4; ni++)
                    s[mi][ni] = __builtin_amdgcn_mfma_f32_16x16x32_bf16(aq[mi], bk[ni], s[mi][ni], 0, 0, 0);
        }
#pragma unroll
        for (int mi = 0; mi < 2; mi++)
#pragma unroll
            for (int ni = 0; ni < 4; ni++)
#pragma unroll
                for (int r = 0; r < 4; r++) s[mi][ni][r] *= 0.125f;

#pragma unroll
        for (int mi = 0; mi < 2; mi++) {
#pragma unroll
            for (int r = 0; r < 4; r++) {
                float rm = fmaxf(fmaxf(s[mi][0][r], s[mi][1][r]), fmaxf(s[mi][2][r], s[mi][3][r]));
#pragma unroll
                for (int d = 1; d < 16; d <<= 1) rm = fmaxf(rm, __shfl_xor(rm, d));
                const float mn = fmaxf(m_st[mi][r], rm);
                const float alpha = __expf(m_st[mi][r] - mn);
                float rsum = 0.f;
#pragma unroll
                for (int ni = 0; ni < 4; ni++) {
                    float p = __expf(s[mi][ni][r] - mn);
                    s[mi][ni][r] = p;
                    rsum += p;
                }
#pragma unroll
                for (int d = 1; d < 16; d <<= 1) rsum += __shfl_xor(rsum, d);
                l_st[mi][r] = l_st[mi][r] * alpha + rsum;
                m_st[mi][r] = mn;
#pragma unroll
                for (int ni = 0; ni < 4; ni++) o[mi][ni][r] *= alpha;
#pragma unroll
                for (int ni = 0; ni < 4; ni++)
                    sP[wv][(mi * 16 + quad * 4 + r) * 64 + ni * 16 + l15] = f2bf(s[mi][ni][r]);
            }
        }

#pragma unroll
        for (int ks = 0; ks < 2; ks++) {
            bf16x8 ap[2], bv2[4];
#pragma unroll
            for (int mi = 0; mi < 2; mi++)
                ap[mi] = *(const bf16x8*)(&sP[wv][(mi * 16 + l15) * 64 + ks * 32 + quad * 8]);
#pragma unroll
            for (int ni = 0; ni < 4; ni++)
                bv2[ni] = *(const bf16x8*)(sVT + (ni * 16 + l15) * 64 + ks * 32 + quad * 8);
#pragma unroll
            for (int mi = 0; mi < 2; mi++)
#pragma unroll
                for (int ni = 0; ni < 4; ni++)
                    o[mi][ni] = __builtin_amdgcn_mfma_f32_16x16x32_bf16(ap[mi], bv2[ni], o[mi][ni], 0, 0, 0);
        }
    }

#pragma unroll
    for (int mi = 0; mi < 2; mi++) {
#pragma unroll
        for (int r = 0; r < 4; r++) {
            const float inv = 1.0f / l_st[mi][r];
            const int row = qbase + wq + mi * 16 + quad * 4 + r;
#pragma unroll
            for (int ni = 0; ni < 4; ni++) {
                const int col = h * 64 + ni * 16 + l15;
                attn_o[(size_t)row * 1024 + col] = f2bf(o[mi][ni][r] * inv);
            }
        }
    }
}

// ---------------------------------------------------------------------------
extern "C" void kernel_launch(void* const* d_in, const int* in_sizes, int n_in,
                              void* d_out, int out_size, void* d_ws, size_t ws_size,
                              hipStream_t stream) {
    const float* x      = (const float*)d_in[0];
    const float* mv_n   = (const float*)d_in[1];
    const float* mv_c   = (const float*)d_in[2];
    const float* qkv_w  = (const float*)d_in[3];
    const float* qkv_b  = (const float*)d_in[4];
    const float* proj_w = (const float*)d_in[5];
    const float* proj_b = (const float*)d_in[6];
    const float* mv_w1  = (const float*)d_in[7];
    const float* mv_b1  = (const float*)d_in[8];
    const float* mv_w2  = (const float*)d_in[9];
    const float* mv_b2  = (const float*)d_in[10];
    const float* mlp_w1 = (const float*)d_in[11];
    const float* mlp_b1 = (const float*)d_in[12];
    const float* mlp_w2 = (const float*)d_in[13];
    const float* mlp_b2 = (const float*)d_in[14];
    float* out = (float*)d_out;

    char* ws = (char*)d_ws;
    size_t off = 0;
    auto alloc = [&](size_t bytes) {
        char* p = ws + off;
        off += (bytes + 255) & ~(size_t)255;
        return p;
    };
    ushort_t* w_qkv_t  = (ushort_t*)alloc((size_t)3072 * 1024 * 2);
    ushort_t* w_proj_t = (ushort_t*)alloc((size_t)1024 * 1024 * 2);
    ushort_t* w_mv1_t  = (ushort_t*)alloc((size_t)4096 * 9216 * 2);
    ushort_t* w_mv2_t  = (ushort_t*)alloc((size_t)1024 * 4096 * 2);
    ushort_t* w_mlp1_t = (ushort_t*)alloc((size_t)4096 * 1024 * 2);
    ushort_t* w_mlp2_t = (ushort_t*)alloc((size_t)1024 * 4096 * 2);
    ushort_t* lnbuf    = (ushort_t*)alloc((size_t)16384 * 1024 * 2);
    ushort_t* qkvmid   = (ushort_t*)alloc((size_t)16384 * 4096 * 2);
    ushort_t* attn_o   = (ushort_t*)alloc((size_t)16384 * 1024 * 2);
    float*    xacc     = (float*)alloc((size_t)16384 * 1024 * 4);
    ushort_t* acat     = (ushort_t*)alloc((size_t)16384 * 9216 * 2);

    // weights -> bf16 [M][K]
    wt_transpose<<<dim3(3072 / 64, 1024 / 64), 256, 0, stream>>>(qkv_w, w_qkv_t, 1024, 3072);
    wt_transpose<<<dim3(1024 / 64, 1024 / 64), 256, 0, stream>>>(proj_w, w_proj_t, 1024, 1024);
    wt_transpose<<<dim3(4096 / 64, 9216 / 64), 256, 0, stream>>>(mv_w1, w_mv1_t, 9216, 4096);
    wt_transpose<<<dim3(1024 / 64, 4096 / 64), 256, 0, stream>>>(mv_w2, w_mv2_t, 4096, 1024);
    wt_transpose<<<dim3(4096 / 64, 1024 / 64), 256, 0, stream>>>(mlp_w1, w_mlp1_t, 1024, 4096);
    wt_transpose<<<dim3(1024 / 64, 4096 / 64), 256, 0, stream>>>(mlp_w2, w_mlp2_t, 4096, 1024);

    // MSA branch (rolled domain)
    ln_kernel<<<16384, 256, 0, stream>>>(x, lnbuf, 1024, SHIFT_T);
    gemm256<<<dim3(12, 64), 512, 0, stream>>>(lnbuf, w_qkv_t, qkv_b, nullptr, nullptr, qkvmid,
                                              1024, 3072, 0, 0);
    attn_kernel<<<dim3(4, 16, 32), 256, 0, stream>>>(qkvmid, attn_o);
    gemm256<<<dim3(4, 64), 512, 0, stream>>>(attn_o, w_proj_t, proj_b, x, xacc, nullptr,
                                             1024, 1024, 2, 1);

    // mv conditioning branch
    ln_kernel<<<16384, 256, 0, stream>>>(xacc, acat, 9216, 0);
    cvt_cat<<<dim3(65536, 2), 256, 0, stream>>>(mv_n, mv_c, acat);
    gemm256<<<dim3(16, 64), 512, 0, stream>>>(acat, w_mv1_t, mv_b1, nullptr, nullptr, qkvmid,
                                              9216, 4096, 1, 0);
    gemm256<<<dim3(4, 64), 512, 0, stream>>>(qkvmid, w_mv2_t, mv_b2, xacc, xacc, nullptr,
                                             4096, 1024, 2, 0);

    // FFN branch
    ln_kernel<<<16384, 256, 0, stream>>>(xacc, lnbuf, 1024, 0);
    gemm256<<<dim3(16, 64), 512, 0, stream>>>(lnbuf, w_mlp1_t, mlp_b1, nullptr, nullptr, qkvmid,
                                              1024, 4096, 1, 0);
    gemm256<<<dim3(4, 64), 512, 0, stream>>>(qkvmid, w_mlp2_t, mlp_b2, xacc, out, nullptr,
                                             4096, 1024, 2, 0);
}